// Round 3
// baseline (341.661 us; speedup 1.0000x reference)
//
#include <hip/hip_runtime.h>
#include <stdint.h>

namespace {

constexpr int SEQ    = 250;
constexpr int SPAN   = 50;
constexpr int NSPANS = 3;
constexpr int NATT   = 15;
constexpr int QS     = 95;   // QRS_START
constexpr int QE     = 155;  // QRS_END
constexpr int NB     = 16384;
constexpr int NCH    = 12;
constexpr uint32_t HI = 200; // exclusive upper bound for starts

struct U2 { uint32_t a, b; };

// Threefry-2x32, 20 rounds — bit-exact replica of jax/_src/prng.py
__host__ __device__ constexpr U2 tf2x32(uint32_t k0, uint32_t k1,
                                        uint32_t x0, uint32_t x1) {
  uint32_t ks[3] = { k0, k1, k0 ^ k1 ^ 0x1BD11BDAu };
  uint32_t rot[2][4] = { {13u, 15u, 26u, 6u}, {17u, 29u, 16u, 24u} };
  x0 += ks[0];
  x1 += ks[1];
  for (int i = 0; i < 5; ++i) {
    for (int j = 0; j < 4; ++j) {
      uint32_t r = rot[i & 1][j];
      x0 += x1;
      x1 = (x1 << r) | (x1 >> (32u - r));
      x1 ^= x0;
    }
    x0 += ks[(i + 1) % 3];
    x1 += ks[(i + 2) % 3] + (uint32_t)(i + 1);
  }
  return U2{x0, x1};
}

// ---- PARTITIONABLE threefry semantics (jax_threefry_partitionable=True):
//   split(key, n): subkey j = (tf(key,0,j).a, tf(key,0,j).b)   [no XOR]
//   random_bits(key, 32, shape): out[i] = tf(key,0,i).a ^ tf(key,0,i).b [XOR]
//
// jax.random.key(42) => raw key (0, 42)
constexpr U2 SK1 = tf2x32(0u, 42u, 0u, 0u);  // k1: uniform(use_physio)
constexpr U2 SK2 = tf2x32(0u, 42u, 0u, 1u);  // k2: candidate randint
constexpr U2 SK3 = tf2x32(0u, 42u, 0u, 2u);  // k3: fallback randint

// randint's internal split(key, 2): hi-bits key counter (0,0), lo-bits (0,1)
constexpr U2 K2H = tf2x32(SK2.a, SK2.b, 0u, 0u);
constexpr U2 K2L = tf2x32(SK2.a, SK2.b, 0u, 1u);
constexpr U2 K3H = tf2x32(SK3.a, SK3.b, 0u, 0u);
constexpr U2 K3L = tf2x32(SK3.a, SK3.b, 0u, 1u);

// 32-bit random bits draw, partitionable path: XOR of both output words
__device__ __forceinline__ uint32_t rbit(U2 k, uint32_t idx) {
  U2 r = tf2x32(k.a, k.b, 0u, idx);
  return r.a ^ r.b;
}

// jax randint(0,200): multiplier = (2^16 % 200)^2 % 200 = 96
__device__ __forceinline__ uint32_t draw200(uint32_t h, uint32_t l) {
  return ((h % HI) * 96u + (l % HI)) % HI;
}

__global__ void k_starts(int* __restrict__ starts) {
  constexpr uint32_t NU = (uint32_t)NB * NSPANS;  // 49152
  int t = blockIdx.x * blockDim.x + threadIdx.x;
  if (t >= (int)NU) return;

  // use_physio = uniform(k1) < 0.8 ; u = bitcast((bits>>9)|0x3f800000) - 1
  uint32_t ub = rbit(SK1, (uint32_t)t);
  float u = __uint_as_float((ub >> 9) | 0x3f800000u) - 1.0f;
  bool physio = (u < 0.8f);

  int chosen = -1;
  for (int a = 0; a < NATT; ++a) {
    uint32_t idx = (uint32_t)t * NATT + (uint32_t)a;  // flat (B,S,A) index
    uint32_t h = rbit(K2H, idx);
    uint32_t l = rbit(K2L, idx);
    int cand = (int)draw200(h, l);
    // ends = min(cand+50, 250) <= 249; no_overlap = (end<=95) | (cand>=155)
    bool no_ov = (cand + SPAN <= QS) || (cand >= QE);
    if (no_ov || !physio) { chosen = cand; break; }  // argmax = first valid
  }

  int st;
  if (chosen >= 0) {
    st = chosen;
  } else {
    uint32_t h = rbit(K3H, (uint32_t)t);
    uint32_t l = rbit(K3L, (uint32_t)t);
    st = (int)draw200(h, l);
  }
  starts[t] = st;
}

// masked_x: one float4 per thread; 3000 % 4 == 0 so a float4 never crosses a
// batch boundary (channel-row crossings are fine: mask depends only on pos).
__global__ void k_mask_x(const float4* __restrict__ x4, float4* __restrict__ o4,
                         const int* __restrict__ starts) {
  constexpr int NV = NB * NCH * SEQ / 4;  // 12,288,000
  int tid = blockIdx.x * blockDim.x + threadIdx.x;
  if (tid >= NV) return;
  int f = tid << 2;
  int b = f / (NCH * SEQ);
  int r = f - b * (NCH * SEQ);
  int pos0 = r % SEQ;
  int s0 = starts[b * 3 + 0];
  int s1 = starts[b * 3 + 1];
  int s2 = starts[b * 3 + 2];
  float4 v = x4[tid];
  float vv[4] = { v.x, v.y, v.z, v.w };
#pragma unroll
  for (int j = 0; j < 4; ++j) {
    int p = pos0 + j;
    if (p >= SEQ) p -= SEQ;  // wrap into next channel row (same batch)
    bool m = ((unsigned)(p - s0) < (unsigned)SPAN) ||
             ((unsigned)(p - s1) < (unsigned)SPAN) ||
             ((unsigned)(p - s2) < (unsigned)SPAN);
    if (m) vv[j] = 0.0f;
  }
  o4[tid] = make_float4(vv[0], vv[1], vv[2], vv[3]);
}

// masks as float 1.0/0.0; 250 % 4 != 0 so compute b per element (stores are
// still contiguous float4).
__global__ void k_mask_out(float4* __restrict__ m4, const int* __restrict__ starts) {
  constexpr int NM4 = NB * SEQ / 4;  // 1,024,000
  int tid = blockIdx.x * blockDim.x + threadIdx.x;
  if (tid >= NM4) return;
  int f = tid << 2;
  float vv[4];
#pragma unroll
  for (int j = 0; j < 4; ++j) {
    int i = f + j;
    int b = i / SEQ;
    int p = i - b * SEQ;
    bool m = ((unsigned)(p - starts[b * 3 + 0]) < (unsigned)SPAN) ||
             ((unsigned)(p - starts[b * 3 + 1]) < (unsigned)SPAN) ||
             ((unsigned)(p - starts[b * 3 + 2]) < (unsigned)SPAN);
    vv[j] = m ? 1.0f : 0.0f;
  }
  m4[tid] = make_float4(vv[0], vv[1], vv[2], vv[3]);
}

}  // namespace

extern "C" void kernel_launch(void* const* d_in, const int* in_sizes, int n_in,
                              void* d_out, int out_size, void* d_ws, size_t ws_size,
                              hipStream_t stream) {
  const float* x = (const float*)d_in[0];
  float* out = (float*)d_out;                          // masked_x: 16384*12*250
  float* mask_out = out + (size_t)NB * NCH * SEQ;      // masks:    16384*250
  int* starts = (int*)d_ws;                            // 49152 ints (192 KiB)

  k_starts<<<(NB * NSPANS + 255) / 256, 256, 0, stream>>>(starts);
  k_mask_x<<<(NB * NCH * SEQ / 4) / 256, 256, 0, stream>>>(
      (const float4*)x, (float4*)out, starts);
  k_mask_out<<<(NB * SEQ / 4 + 255) / 256, 256, 0, stream>>>(
      (float4*)mask_out, starts);
}